// Round 1
// baseline (54.069 us; speedup 1.0000x reference)
//
#include <hip/hip_runtime.h>

// WideModel: 8 hashed multi-hot features + sparse linear combine.
// f0..f5: bucket=100000, s0..s1: bucket=1000000. x: [B,L] int32, -1 = pad.
// out[b] = bias + sum_f sum_{distinct bins in row} W_f[bin]

constexpr int B = 16384;
constexpr int L = 50;

struct Args {
    const int*   x[8];
    const float* w[8];
    const float* bias;
    float*       out;
};

__global__ __launch_bounds__(256) void wide_kernel(Args a) {
    const int lane = threadIdx.x & 63;
    const int row  = blockIdx.x * 4 + (threadIdx.x >> 6);

    float acc = 0.0f;

    #pragma unroll
    for (int f = 0; f < 8; ++f) {
        // lanes 0..49 load the row's values; others act as padding
        int v = -1;
        if (lane < L) v = a.x[f][row * L + lane];

        unsigned m;
        if (f < 6) m = (unsigned)v % 100000u;   // magic-mul, compile-time divisor
        else       m = (unsigned)v % 1000000u;
        // sentinel must be >= bucket so pad lanes never alias a valid bin
        const unsigned bin = (v >= 0) ? m : 0xFFFFFFFFu;

        // keep-first dedupe: lane i keeps iff no lane j<i has the same bin.
        bool keep = (v >= 0);
        #pragma unroll
        for (int j = 0; j < L - 1; ++j) {       // j = 0..48 (max needed: lane 49)
            const unsigned bj = __builtin_amdgcn_readlane(bin, j);
            if (lane > j && bj == bin) keep = false;
        }

        if (keep) acc += a.w[f][bin];
    }

    // wave-wide sum (64 lanes; pad lanes contributed 0)
    #pragma unroll
    for (int off = 32; off; off >>= 1)
        acc += __shfl_xor(acc, off);

    if (lane == 0) a.out[row] = acc + a.bias[0];
}

extern "C" void kernel_launch(void* const* d_in, const int* in_sizes, int n_in,
                              void* d_out, int out_size, void* d_ws, size_t ws_size,
                              hipStream_t stream) {
    Args a;
    for (int i = 0; i < 8; ++i) a.x[i] = (const int*)d_in[i];
    for (int i = 0; i < 8; ++i) a.w[i] = (const float*)d_in[8 + i];
    a.bias = (const float*)d_in[16];
    a.out  = (float*)d_out;

    wide_kernel<<<B / 4, 256, 0, stream>>>(a);
}

// Round 2
// 39.497 us; speedup vs baseline: 1.3689x; 1.3689x over previous
//
#include <hip/hip_runtime.h>

// WideModel: 8 hashed multi-hot features + sparse linear combine.
// Strategy: one THREAD per (row, feature). Load 50 ints, mod by compile-time
// bucket, sort in registers with a pruned Batcher odd-even merge network,
// dedupe via adjacent-compare, gather W, atomicAdd partial into out[row].
// out is pre-initialized to bias by a small init kernel each call.

constexpr int B = 16384;
constexpr int L = 50;

// ---- compile-time Batcher odd-even mergesort network for n=64, pruned ----
// Pads (slots 50..63) start at 0xFFFFFFFF (the max value) and provably never
// move in an ascending network, so every comparator touching a slot >= 50 is
// a no-op and is pruned at compile time.
struct Net {
    unsigned char a[560];
    unsigned char b[560];
    int n;
};

constexpr Net make_net() {
    Net r{};
    int c = 0;
    for (int p = 1; p < 64; p <<= 1)
        for (int k = p; k >= 1; k >>= 1)
            for (int j = (k == p ? 0 : k); j + k < 64; j += 2 * k)
                for (int i = 0; i < k && i + j + k < 64; ++i)
                    if ((i + j) / (2 * p) == (i + j + k) / (2 * p) &&
                        (i + j + k) < L) {
                        r.a[c] = (unsigned char)(i + j);
                        r.b[c] = (unsigned char)(i + j + k);
                        ++c;
                    }
    r.n = c;
    return r;
}

inline constexpr Net NET = make_net();

struct KArgs {
    const int*   x[8];
    const float* w[8];
    const float* bias;
    float*       out;
};

template <unsigned BUCKET>
__device__ __forceinline__ void feat_body(const int* __restrict__ xp,
                                          const float* __restrict__ W,
                                          float* __restrict__ outp) {
    unsigned v[L];

    // ---- load 50 ints as 25x int2 (row*200 B is 8-aligned) ----
    #pragma unroll
    for (int i = 0; i < L / 2; ++i) {
        int2 t = reinterpret_cast<const int2*>(xp)[i];
        v[2 * i]     = (unsigned)t.x;
        v[2 * i + 1] = (unsigned)t.y;
    }

    // ---- hash: mod by compile-time bucket; pad (-1) -> 0xFFFFFFFF ----
    #pragma unroll
    for (int i = 0; i < L; ++i) {
        int s = (int)v[i];
        v[i] = (s >= 0) ? ((unsigned)s % BUCKET) : 0xFFFFFFFFu;
    }

    // ---- sort ascending (pads sink to the end) ----
    #pragma unroll
    for (int c = 0; c < NET.n; ++c) {
        const int ia = NET.a[c];
        const int ib = NET.b[c];
        const unsigned va = v[ia];
        const unsigned vb = v[ib];
        const unsigned lo = va < vb ? va : vb;
        const unsigned hi = va < vb ? vb : va;
        v[ia] = lo;
        v[ib] = hi;
    }

    // ---- dedupe + gather + sum ----
    float acc = 0.0f;
    unsigned prev = 0xFFFFFFFFu;  // != any valid bin (< BUCKET)
    #pragma unroll
    for (int i = 0; i < L; ++i) {
        const unsigned b = v[i];
        if ((b != prev) & (b < BUCKET)) acc += W[b];
        prev = b;
    }

    atomicAdd(outp, acc);
}

__global__ __launch_bounds__(256) void wide_feat_kernel(KArgs a) {
    const int tid  = blockIdx.x * 256 + (int)threadIdx.x;
    const int feat = tid >> 14;        // 16384 rows per feature
    const int row  = tid & (B - 1);

    const int* xp = a.x[feat] + row * L;

    if (feat < 6)
        feat_body<100000u>(xp, a.w[feat], &a.out[row]);
    else
        feat_body<1000000u>(xp, a.w[feat], &a.out[row]);
}

__global__ __launch_bounds__(256) void init_kernel(float* out, const float* bias) {
    const int i = blockIdx.x * 256 + (int)threadIdx.x;
    out[i] = bias[0];
}

extern "C" void kernel_launch(void* const* d_in, const int* in_sizes, int n_in,
                              void* d_out, int out_size, void* d_ws, size_t ws_size,
                              hipStream_t stream) {
    KArgs a;
    for (int i = 0; i < 8; ++i) a.x[i] = (const int*)d_in[i];
    for (int i = 0; i < 8; ++i) a.w[i] = (const float*)d_in[8 + i];
    a.bias = (const float*)d_in[16];
    a.out  = (float*)d_out;

    init_kernel<<<B / 256, 256, 0, stream>>>(a.out, a.bias);
    wide_feat_kernel<<<(8 * B) / 256, 256, 0, stream>>>(a);
}